// Round 7
// baseline (259.270 us; speedup 1.0000x reference)
//
#include <hip/hip_runtime.h>

// SSIM loss, fused: (32,3,512,512) fp32, 11x11 avg pools, out = 1 - mean(ssim_map).
//
// R9 (resubmit; previous round failed on container acquisition, not kernel).
// R9 = R8 structure frozen; VALU-overhead strip (addressing/swizzle/guards).
//  Measured basis: R8 = 113us, VALUBusy 43% (~48.6us issue) vs ~17us semantic
//  FLOPs -> ~2/3 of VALU is overhead. Conflicts at floor (2.76e6). Changes:
//  - Swizzle simplified to per-thread constants. Every LDS op's 8-lane phase
//    is same-row here (stores: 1 row x 8 xr; reads: 8 consecutive lanes, 1
//    row), so the slot term in the key was never needed:
//      store: (slot<<6) + xr*8 + (k^xr)   (k^xr spreads the 8 store lanes)
//      read:  (slot<<6) + lx,  lx = lane ^ ((lane>>3)&7)  (bijective/phase)
//    Removes the per-access (sl&7)-xor chains.
//  - Load addressing hoisted: clamped col offsets goff[6] + edge masks xm[6]
//    computed once per strip; per chunk the row pointer advances +32*512.
//    Edge-mask multiply only for bx in {0,7} (block-uniform). Row guards only
//    at head and last prefetch (c==14); chunks 0..13 load guard-free.
//  - Ring indices are incremental (+64 / +32 with wrap subtract), slot map
//    slot(r) = (r+5) mod 48.
//  Carried verified: 768 persistent blocks (3/CU), 48-slot ring, 32 rows/chunk,
//  LDS-only barriers (no vmcnt drain; prefetch in flight across them),
//  prefetch-before-stageC + sched_barrier(0), rcp+NR division, separate
//  finalize kernel (R5 threadfence lesson), one double atomic per block.

#define IMGW 512
#define IMGPIX (IMGW * IMGW)
#define CH 32            // output rows per chunk
#define NCHUNK 16        // 512 / CH
#define NBUF 48          // ring slots (rows)
#define RING (NBUF * 64) // ring size in float4
#define PBLOCKS 768      // 8 col-strips x 96 images, 3 per CU

__global__ __launch_bounds__(256, 3)
void ssim_strip(const float* __restrict__ pred,
                const float* __restrict__ target,
                double* __restrict__ accum)
{
    __shared__ float4 sH[RING];          // 49152 B -> 3 blocks/CU
    __shared__ double wpart[4];

    const int tid = threadIdx.x;
    const int img = blockIdx.x >> 3, bx = blockIdx.x & 7;
    const float* __restrict__ p = pred   + (size_t)img * IMGPIX;
    const float* __restrict__ t = target + (size_t)img * IMGPIX;

    const int j    = tid >> 3;           // staging row 0..31
    const int xr   = tid & 7;            // 8-col run
    const int xbase = bx * 64 + xr * 8;
    const int lane = tid & 63;
    const int w    = tid >> 6;
    const int lx   = lane ^ ((lane >> 3) & 7);    // read swizzle, per-thread const
    const bool edge = (bx == 0) || (bx == 7);     // block-uniform

    // per-thread clamped column offsets + x-validity masks (constant per strip)
    int goff[6]; float xm[6];
#pragma unroll
    for (int c2 = 0; c2 < 6; ++c2) {
        const int gx = xbase - 8 + 4 * c2;        // multiple of 4 -> aligned
        xm[c2] = ((unsigned)gx < (unsigned)IMGW) ? 1.f : 0.f;
        goff[c2] = gx < 0 ? 0 : (gx > IMGW - 4 ? IMGW - 4 : gx);
    }

    float fp[24], ft[24];

    auto apply_edge = [&]() {
#pragma unroll
        for (int c2 = 0; c2 < 6; ++c2) {
            const float m = xm[c2];
#pragma unroll
            for (int q = 0; q < 4; ++q) { fp[4*c2+q] *= m; ft[4*c2+q] *= m; }
        }
    };

    // fast loader: row known valid, pointers pre-offset to the row
    auto loadF = [&](const float* pr, const float* tr) {
#pragma unroll
        for (int c2 = 0; c2 < 6; ++c2) {
            const float4 pv = *(const float4*)(pr + goff[c2]);
            const float4 tv = *(const float4*)(tr + goff[c2]);
            fp[4*c2+0]=pv.x; fp[4*c2+1]=pv.y; fp[4*c2+2]=pv.z; fp[4*c2+3]=pv.w;
            ft[4*c2+0]=tv.x; ft[4*c2+1]=tv.y; ft[4*c2+2]=tv.z; ft[4*c2+3]=tv.w;
        }
        if (edge) apply_edge();
    };

    // guarded loader: row may be OOB (head rows <0, tail rows >511)
    auto loadG = [&](int r) {
        if ((unsigned)r < (unsigned)IMGW) {
            loadF(p + (size_t)r * IMGW, t + (size_t)r * IMGW);
        } else {
#pragma unroll
            for (int i = 0; i < 24; ++i) { fp[i] = 0.f; ft[i] = 0.f; }
        }
    };

    // stage B: horizontal 11-sums of 4 planes from regs -> ring slot sl
    auto stageB = [&](int sl) {
        float s1=0.f, s2=0.f, s3=0.f, s4=0.f;
#pragma unroll
        for (int i = 3; i <= 13; ++i) {
            s1 += fp[i]; s2 += ft[i];
            s3 += fp[i]*fp[i] + ft[i]*ft[i];
            s4 += fp[i]*ft[i];
        }
        const int wbi = (sl << 6) + (xr << 3);
#pragma unroll
        for (int k = 0; k < 8; ++k) {
            if (k) {
                const int a = k + 13, b = k + 2;
                s1 += fp[a] - fp[b];
                s2 += ft[a] - ft[b];
                s3 += (fp[a]*fp[a] + ft[a]*ft[a]) - (fp[b]*fp[b] + ft[b]*ft[b]);
                s4 += fp[a]*ft[a] - fp[b]*ft[b];
            }
            sH[wbi + (k ^ xr)] = make_float4(s1, s2, s3, s4);
        }
    };

    // LDS-only barrier: no vmcnt drain (prefetch loads stay in flight)
    auto barrier_lds = [&]() {
        asm volatile("s_waitcnt lgkmcnt(0)" ::: "memory");
        __builtin_amdgcn_s_barrier();
        asm volatile("" ::: "memory");
    };

    // ---- head: rows -5..26 -> slots j; rows 27..36 -> slots 32+j ----
    loadG(-5 + j);
    stageB(j);
    if (tid < 80) {                      // rows 27..36 (all valid)
        loadF(p + (size_t)(27 + j) * IMGW, t + (size_t)(27 + j) * IMGW);
        stageB(32 + j);
    }
    barrier_lds();

    const float inv = 1.0f / 121.0f;
    const float C1 = 1e-4f, C2 = 9e-4f;

    const float* pf = p + (size_t)(37 + j) * IMGW;   // prefetch row pointer
    const float* tf = t + (size_t)(37 + j) * IMGW;
    int wb = 42 + j; if (wb >= NBUF) wb -= NBUF;     // stage-B slot, chunk 0
    int cs = 8 * w;                                  // stage-C slot, chunk 0
    double acc = 0.0;

    for (int c = 0; c < NCHUNK; ++c) {
        // prefetch next chunk's rows (rows 37+32c+j; valid for c<14)
        if (c < 14)       { loadF(pf, tf); pf += CH * IMGW; tf += CH * IMGW; }
        else if (c == 14) { loadG(485 + j); }
        __builtin_amdgcn_sched_barrier(0);

        // ---- stage C: vertical 11-sums (lane = column), SSIM formula ----
        int ri = (cs << 6) + lx;
        float4 rr[8];
        float4 S = {0.f, 0.f, 0.f, 0.f};
#pragma unroll
        for (int i = 0; i < 10; ++i) {
            const float4 a = sH[ri];
            if (i < 8) rr[i] = a;
            S.x += a.x; S.y += a.y; S.z += a.z; S.w += a.w;
            ri += 64; if (ri >= RING) ri -= RING;
        }
        float tl = 0.f;
#pragma unroll
        for (int k = 0; k < 8; ++k) {
            const float4 nw = sH[ri];
            ri += 64; if (ri >= RING) ri -= RING;
            const float W1 = S.x + nw.x, W2 = S.y + nw.y;
            const float W3 = S.z + nw.z, W4 = S.w + nw.w;
            S.x = W1 - rr[k].x; S.y = W2 - rr[k].y;
            S.z = W3 - rr[k].z; S.w = W4 - rr[k].w;

            const float mu1 = W1*inv, mu2 = W2*inv;
            const float E3  = W3*inv, E12 = W4*inv;
            const float mu11 = mu1*mu1, mu22 = mu2*mu2, mu12 = mu1*mu2;
            const float num = (2.f*mu12 + C1) * (2.f*(E12 - mu12) + C2);
            const float den = (mu11 + mu22 + C1) * ((E3 - mu11 - mu22) + C2);
            float rdn = __builtin_amdgcn_rcpf(den);
            rdn = rdn * __builtin_fmaf(-den, rdn, 2.0f);   // 1 NR step
            tl += num * rdn;
        }
        acc += (double)tl;
        cs += CH; if (cs >= NBUF) cs -= NBUF;

        barrier_lds();                   // stage-C reads done -> ring writable
        if (c < NCHUNK - 1) {
            stageB(wb);                  // consumes prefetched regs (vmcnt wait)
            wb += CH; if (wb >= NBUF) wb -= NBUF;
        }
        barrier_lds();                   // writes visible for next stage C
    }

    // ---- block reduce -> one double atomic per block ----
#pragma unroll
    for (int off = 32; off > 0; off >>= 1)
        acc += __shfl_down(acc, off, 64);
    if (lane == 0) wpart[w] = acc;
    __syncthreads();
    if (tid == 0)
        atomicAdd(accum, wpart[0] + wpart[1] + wpart[2] + wpart[3]);
}

__global__ void ssim_finalize(const double* __restrict__ accum,
                              float* __restrict__ out) {
    const double n = 25165824.0;  // 32*3*512*512
    out[0] = (float)(1.0 - accum[0] / n);
}

extern "C" void kernel_launch(void* const* d_in, const int* in_sizes, int n_in,
                              void* d_out, int out_size, void* d_ws, size_t ws_size,
                              hipStream_t stream) {
    const float* pred   = (const float*)d_in[0];
    const float* target = (const float*)d_in[1];
    float* out = (float*)d_out;
    double* accum = (double*)d_ws;

    hipMemsetAsync(d_ws, 0, sizeof(double), stream);

    ssim_strip<<<dim3(PBLOCKS), dim3(256), 0, stream>>>(pred, target, accum);
    ssim_finalize<<<1, 1, 0, stream>>>(accum, out);
}